// Round 11
// baseline (65.788 us; speedup 1.0000x reference)
//
#include <hip/hip_runtime.h>

#define B_ 32
#define C_ 64          // Cin = Cout
#define H_ 112
#define W_ 112
#define HW (H_ * W_)
#define HTILES 56            // 2-row tiles per image
#define NBLKC (B_ * HTILES)  // 1792, %8==0 for XCD swizzle

#define SLOTS 114            // slot = w+1; slots 0,113 are zeros
#define CHUNK 128            // bytes per (h,slot): 64 cin bf16
#define XROWB (SLOTS * CHUNK)              // 14592 B per (b,h)
#define XT_BYTES ((size_t)B_ * H_ * XROWB) // ~52.3 MB
#define WQ_OFF 131072

// w-split double buffer: bufA = slots 0..65, bufB = slots 64..113.
// 64 % 8 == 0 -> the (slot&7)<<4 swizzle key is identical in bufB-local
// coords, so the SAME verified koff math serves both buffers.
#define AROWB (66 * CHUNK)   // 8448
#define ABUFB (4 * AROWB)    // 33792
#define BROWB (50 * CHUNK)   // 6400
#define BBUFB (4 * BROWB)    // 25600
#define XS_B (ABUFB + BBUFB) // 59392

typedef short bf16x8 __attribute__((ext_vector_type(8)));
typedef float f32x4 __attribute__((ext_vector_type(4)));
typedef unsigned int u32;

#define GLOAD_LDS(g, l, sz)                                                   \
    __builtin_amdgcn_global_load_lds(                                         \
        (const __attribute__((address_space(1))) u32*)(const void*)(g),       \
        (__attribute__((address_space(3))) u32*)(void*)(l), (sz), 0, 0)

__device__ inline unsigned short f2bf(float f) {
    union { float f; unsigned u; } v;
    v.f = f;
    unsigned u = v.u;
    u += 0x7fffu + ((u >> 16) & 1u);   // RNE
    return (unsigned short)(u >> 16);
}

// ---------------------------------------------------------------------------
// Transform (VERIFIED r4-r10, HBM floor): x[b][c][h][w] fp32 ->
// xt[b][h][slot][cin] bf16; dword for cin-pair cp at (cp*4)^((slot&7)<<4)
// inside each 128-B chunk. Blocks 0..17 also pre-pack weights into wq2
// (verified r10).
// ---------------------------------------------------------------------------
__global__ __launch_bounds__(256) void xform(const float* __restrict__ x,
                                             unsigned short* __restrict__ xt,
                                             const float* __restrict__ w,
                                             unsigned short* __restrict__ wq2) {
    __shared__ unsigned short pl[C_ * SLOTS];

    const int tid = threadIdx.x;
    const int b   = blockIdx.x / H_;
    const int h   = blockIdx.x % H_;

#pragma unroll
    for (int it = 0; it < 7; ++it) {
        const int u  = tid + 256 * it;        // < 1792 = 64c * 28 quads
        const int c  = u / 28;
        const int w4 = u % 28;
        const f32x4 v =
            *(const f32x4*)(x + ((size_t)(b * C_ + c) * H_ + h) * W_ + w4 * 4);
        const u32 lo = (u32)f2bf(v[0]) | ((u32)f2bf(v[1]) << 16);
        const u32 hi = (u32)f2bf(v[2]) | ((u32)f2bf(v[3]) << 16);
        u32* p = (u32*)&pl[c * SLOTS + w4 * 4];
        p[0] = lo;
        p[1] = hi;
    }
    __syncthreads();

    unsigned short* xtrow = xt + (size_t)(b * H_ + h) * (XROWB / 2);
#pragma unroll
    for (int it = 0; it < 15; ++it) {
        const int u = tid + 256 * it;         // < 3648 = 114 slots * 32 cps
        if (u < SLOTS * 32) {
            const int slot = u >> 5;
            const int cp   = u & 31;
            u32 val = 0;
            if (1 <= slot && slot <= 112) {
                const int ww = slot - 1;
                val = (u32)pl[(2 * cp) * SLOTS + ww] |
                      ((u32)pl[(2 * cp + 1) * SLOTS + ww] << 16);
            }
            *(u32*)((char*)xtrow + slot * CHUNK +
                    ((cp * 4) ^ ((slot & 7) << 4))) = val;
        }
    }

    // ---- folded weight quantize + per-wave prepack (verified r10) ----
    if (blockIdx.x < 18) {
        const int i    = blockIdx.x * 256 + tid;   // < 4608 = 2*36*64
        const int lane = i & 63;
        const int t    = (i >> 6) % 36;
        const int mw   = i / 2304;
        const int shift = t >> 2;
        const int c0    = (t >> 1) & 1;
        const int m     = t & 1;
        const int dh = shift / 3, dw = shift % 3;
        const int lcol = lane & 15, kg = lane >> 4;
        const int cout = mw * 32 + m * 16 + lcol;
        const int cinb = c0 * 32 + kg * 8;
        bf16x8 pv;
#pragma unroll
        for (int j = 0; j < 8; ++j) {
            const float v = w[((cout * C_ + cinb + j) * 3 + dh) * 3 + dw];
            pv[j] = (v > 0.f) ? (short)0x3F80
                              : ((v < 0.f) ? (short)(unsigned short)0xBF80
                                           : (short)0);
        }
        *(bf16x8*)((char*)wq2 + ((size_t)(mw * 36 + t) * 64 + lane) * 16) = pv;
    }
}

// ---------------------------------------------------------------------------
// Conv implicit GEMM, r10 structure + intra-block w-split pipeline:
//   stage A -> barrier -> issue gload B -> compute cols 0-63 -> store A
//   -> barrier (drains B) -> compute cols 64-111 -> store B (fire&forget).
// Weights register-resident (wt[36], verified r10). Zero global loads and
// zero guards in the MFMA loops; all indexing static.
// ---------------------------------------------------------------------------
__global__ __launch_bounds__(256, 2) void conv_mfma(
    const unsigned short* __restrict__ xt, const unsigned short* __restrict__ wq2,
    const float* __restrict__ bias, const float* __restrict__ scale,
    float* __restrict__ out) {
    __shared__ char xs[XS_B];   // 59392 B -> 2 blocks/CU

    const int tid  = threadIdx.x;
    const int lane = tid & 63;
    const int wave = tid >> 6;
    const int lcol = lane & 15;
    const int kg   = lane >> 4;
    const int mw   = wave >> 1;      // cout half
    const int nw   = wave & 1;       // row within tile

    const int bid = blockIdx.x;
    const int s   = (bid & 7) * (NBLKC / 8) + (bid >> 3);   // XCD-bijective
    const int b   = s / HTILES;
    const int h0  = (s % HTILES) * 2;

    const char* xtc = (const char*)xt + (size_t)b * H_ * XROWB;
    char* bufA = xs;
    char* bufB = xs + ABUFB;

    // ---- preload all 36 weight tiles for this wave (verified r10) ----
    bf16x8 wt[36];
    {
        const char* wp = (const char*)wq2 + (size_t)mw * 36 * 1024 + lane * 16;
#pragma unroll
        for (int t = 0; t < 36; ++t) wt[t] = *(const bf16x8*)(wp + t * 1024);
    }

    const int xrow = h0 - 1 + wave;
    const bool inb = (0 <= xrow) && (xrow < H_);
    const char* srow = xtc + (size_t)xrow * XROWB;   // valid only if inb
    char* dA = bufA + wave * AROWB;
    char* dB = bufB + wave * BROWB;

    // ---- stage bufA (slots 0..65, 8448 B/row); zero OOB rows (A and B) ----
    if (inb) {
        const char* srcA = srow + lane * 16;
#pragma unroll
        for (int ch = 0; ch < 8; ++ch)
            GLOAD_LDS(srcA + ch * 1024, dA + ch * 1024, 16);
        GLOAD_LDS(srow + 8192 + lane * 4, dA + 8192, 4);   // tail 256 B
    } else {
        const f32x4 z = {0.f, 0.f, 0.f, 0.f};
#pragma unroll
        for (int ch = 0; ch < 8; ++ch)
            *(f32x4*)(dA + lane * 16 + ch * 1024) = z;
        if (lane < 16) *(f32x4*)(dA + 8192 + lane * 16) = z;
#pragma unroll
        for (int ch = 0; ch < 6; ++ch)
            *(f32x4*)(dB + lane * 16 + ch * 1024) = z;
        if (lane < 16) *(f32x4*)(dB + 6144 + lane * 16) = z;
    }
    __syncthreads();

    // ---- issue bufB gloads (slots 64..113, 6400 B/row); land under A ----
    if (inb) {
        const char* srcB = srow + 8192 + lane * 16;
#pragma unroll
        for (int ch = 0; ch < 6; ++ch)
            GLOAD_LDS(srcB + ch * 1024, dB + ch * 1024, 16);
        GLOAD_LDS(srow + 14336 + lane * 4, dB + 6144, 4);  // tail 256 B
    }

    // swizzle-adjusted K-offsets (verified r4; same for both buffers)
    int koff[3][2];
#pragma unroll
    for (int dw = 0; dw < 3; ++dw) {
        const int key = ((lcol + dw) & 7) << 4;
        koff[dw][0] = (kg * 16) ^ key;
        koff[dw][1] = (64 + kg * 16) ^ key;
    }

    const float sc = scale[0];
    f32x4 bs[2];
#pragma unroll
    for (int m = 0; m < 2; ++m)
        bs[m] = *(const f32x4*)(bias + mw * 32 + m * 16 + kg * 4);

    // ---- phase A: cols 0..63 (4 N-frags) ----
    {
        f32x4 acc[2][4];
#pragma unroll
        for (int m = 0; m < 2; ++m)
#pragma unroll
            for (int nf = 0; nf < 4; ++nf)
                acc[m][nf] = (f32x4){0.f, 0.f, 0.f, 0.f};

#pragma unroll
        for (int dh = 0; dh < 3; ++dh) {
            const char* rowb = bufA + (nw + dh) * AROWB;
#pragma unroll
            for (int dw = 0; dw < 3; ++dw) {
                const char* colb = rowb + (lcol + dw) * CHUNK;
#pragma unroll
                for (int c0 = 0; c0 < 2; ++c0) {
                    const int t0 = ((dh * 3 + dw) * 2 + c0) * 2;
                    const char* cb = colb + koff[dw][c0];
#pragma unroll
                    for (int nf = 0; nf < 4; ++nf) {
                        const bf16x8 bv = *(const bf16x8*)(cb + nf * 2048);
                        acc[0][nf] = __builtin_amdgcn_mfma_f32_16x16x32_bf16(
                            wt[t0 + 0], bv, acc[0][nf], 0, 0, 0);
                        acc[1][nf] = __builtin_amdgcn_mfma_f32_16x16x32_bf16(
                            wt[t0 + 1], bv, acc[1][nf], 0, 0, 0);
                    }
                }
            }
        }

        const int h = h0 + nw;
#pragma unroll
        for (int m = 0; m < 2; ++m) {
            const int cobase = mw * 32 + m * 16 + kg * 4;
#pragma unroll
            for (int nf = 0; nf < 4; ++nf) {
                const int col = nf * 16 + lcol;
#pragma unroll
                for (int rr = 0; rr < 4; ++rr)
                    out[((size_t)(b * C_ + cobase + rr)) * HW + h * W_ + col] =
                        sc * (acc[m][nf][rr] + bs[m][rr]);
            }
        }
    }

    __syncthreads();   // drains bufB gloads (issued ~1 compute-phase ago)

    // ---- phase B: cols 64..111 (3 N-frags) ----
    {
        f32x4 acc[2][3];
#pragma unroll
        for (int m = 0; m < 2; ++m)
#pragma unroll
            for (int nf = 0; nf < 3; ++nf)
                acc[m][nf] = (f32x4){0.f, 0.f, 0.f, 0.f};

#pragma unroll
        for (int dh = 0; dh < 3; ++dh) {
            const char* rowb = bufB + (nw + dh) * BROWB;
#pragma unroll
            for (int dw = 0; dw < 3; ++dw) {
                const char* colb = rowb + (lcol + dw) * CHUNK;
#pragma unroll
                for (int c0 = 0; c0 < 2; ++c0) {
                    const int t0 = ((dh * 3 + dw) * 2 + c0) * 2;
                    const char* cb = colb + koff[dw][c0];
#pragma unroll
                    for (int nf = 0; nf < 3; ++nf) {
                        const bf16x8 bv = *(const bf16x8*)(cb + nf * 2048);
                        acc[0][nf] = __builtin_amdgcn_mfma_f32_16x16x32_bf16(
                            wt[t0 + 0], bv, acc[0][nf], 0, 0, 0);
                        acc[1][nf] = __builtin_amdgcn_mfma_f32_16x16x32_bf16(
                            wt[t0 + 1], bv, acc[1][nf], 0, 0, 0);
                    }
                }
            }
        }

        const int h = h0 + nw;
#pragma unroll
        for (int m = 0; m < 2; ++m) {
            const int cobase = mw * 32 + m * 16 + kg * 4;
#pragma unroll
            for (int nf = 0; nf < 3; ++nf) {
                const int col = 64 + nf * 16 + lcol;
#pragma unroll
                for (int rr = 0; rr < 4; ++rr)
                    out[((size_t)(b * C_ + cobase + rr)) * HW + h * W_ + col] =
                        sc * (acc[m][nf][rr] + bs[m][rr]);
            }
        }
    }
}

extern "C" void kernel_launch(void* const* d_in, const int* in_sizes, int n_in,
                              void* d_out, int out_size, void* d_ws,
                              size_t ws_size, hipStream_t stream) {
    const float* x     = (const float*)d_in[0];
    const float* w     = (const float*)d_in[1];
    const float* bias  = (const float*)d_in[2];
    const float* scale = (const float*)d_in[3];
    float* out         = (float*)d_out;

    unsigned short* wq2 = (unsigned short*)d_ws;  // 73728 B prepacked weights
    unsigned short* xt  = (unsigned short*)((char*)d_ws + WQ_OFF);

    xform<<<B_ * H_, 256, 0, stream>>>(x, xt, w, wq2);
    conv_mfma<<<NBLKC, 256, 0, stream>>>(xt, wq2, bias, scale, out);
}

// Round 12
// 65.291 us; speedup vs baseline: 1.0076x; 1.0076x over previous
//
#include <hip/hip_runtime.h>

#define B_ 32
#define C_ 64          // Cin = Cout
#define H_ 112
#define W_ 112
#define HW (H_ * W_)
#define HTILES 56            // 2-row tiles per image
#define NBLKC (B_ * HTILES)  // 1792, %8==0 for XCD swizzle

#define SLOTS 114            // slot = w+1; slots 0,113 are zeros
#define CHUNK 128            // bytes per (h,slot): 64 cin bf16
#define XROWB (SLOTS * CHUNK)              // 14592 B per (b,h)
#define XT_BYTES ((size_t)B_ * H_ * XROWB) // ~52.3 MB
#define WQ_OFF 131072

typedef short bf16x8 __attribute__((ext_vector_type(8)));
typedef float f32x4 __attribute__((ext_vector_type(4)));
typedef unsigned int u32;

#define GLOAD_LDS(g, l, sz)                                                   \
    __builtin_amdgcn_global_load_lds(                                         \
        (const __attribute__((address_space(1))) u32*)(const void*)(g),       \
        (__attribute__((address_space(3))) u32*)(void*)(l), (sz), 0, 0)

__device__ inline unsigned short f2bf(float f) {
    union { float f; unsigned u; } v;
    v.f = f;
    unsigned u = v.u;
    u += 0x7fffu + ((u >> 16) & 1u);   // RNE
    return (unsigned short)(u >> 16);
}

// ---------------------------------------------------------------------------
// Transform (VERIFIED r4-r11, HBM floor): x[b][c][h][w] fp32 ->
// xt[b][h][slot][cin] bf16; dword for cin-pair cp at (cp*4)^((slot&7)<<4)
// inside each 128-B chunk.
// Blocks 0..17 additionally pre-pack quantized weights into wq2:
// wq2[mw][t][lane] 16-B entries, t=(shift*2+c0)*2+m, matching the conv
// K-loop's A-fragment consumption order. Tile loads are 1-KB coalesced.
// ---------------------------------------------------------------------------
__global__ __launch_bounds__(256) void xform(const float* __restrict__ x,
                                             unsigned short* __restrict__ xt,
                                             const float* __restrict__ w,
                                             unsigned short* __restrict__ wq2) {
    __shared__ unsigned short pl[C_ * SLOTS];

    const int tid = threadIdx.x;
    const int b   = blockIdx.x / H_;
    const int h   = blockIdx.x % H_;

#pragma unroll
    for (int it = 0; it < 7; ++it) {
        const int u  = tid + 256 * it;        // < 1792 = 64c * 28 quads
        const int c  = u / 28;
        const int w4 = u % 28;
        const f32x4 v =
            *(const f32x4*)(x + ((size_t)(b * C_ + c) * H_ + h) * W_ + w4 * 4);
        const u32 lo = (u32)f2bf(v[0]) | ((u32)f2bf(v[1]) << 16);
        const u32 hi = (u32)f2bf(v[2]) | ((u32)f2bf(v[3]) << 16);
        u32* p = (u32*)&pl[c * SLOTS + w4 * 4];
        p[0] = lo;
        p[1] = hi;
    }
    __syncthreads();

    unsigned short* xtrow = xt + (size_t)(b * H_ + h) * (XROWB / 2);
#pragma unroll
    for (int it = 0; it < 15; ++it) {
        const int u = tid + 256 * it;         // < 3648 = 114 slots * 32 cps
        if (u < SLOTS * 32) {
            const int slot = u >> 5;
            const int cp   = u & 31;
            u32 val = 0;
            if (1 <= slot && slot <= 112) {
                const int ww = slot - 1;
                val = (u32)pl[(2 * cp) * SLOTS + ww] |
                      ((u32)pl[(2 * cp + 1) * SLOTS + ww] << 16);
            }
            *(u32*)((char*)xtrow + slot * CHUNK +
                    ((cp * 4) ^ ((slot & 7) << 4))) = val;
        }
    }

    // ---- folded weight quantize + per-wave prepack (4608 threads) ----
    if (blockIdx.x < 18) {
        const int i = blockIdx.x * 256 + tid;   // < 4608 = 2*36*64
        const int lane = i & 63;
        const int t    = (i >> 6) % 36;
        const int mw   = i / 2304;
        const int shift = t >> 2;
        const int c0    = (t >> 1) & 1;
        const int m     = t & 1;
        const int dh = shift / 3, dw = shift % 3;
        const int lcol = lane & 15, kg = lane >> 4;
        const int cout = mw * 32 + m * 16 + lcol;
        const int cinb = c0 * 32 + kg * 8;
        unsigned short pk[8];
#pragma unroll
        for (int j = 0; j < 8; ++j) {
            const float v = w[((cout * C_ + cinb + j) * 3 + dh) * 3 + dw];
            pk[j] = (v > 0.f) ? (unsigned short)0x3F80
                              : ((v < 0.f) ? (unsigned short)0xBF80
                                           : (unsigned short)0);
        }
        bf16x8 pv;
#pragma unroll
        for (int j = 0; j < 8; ++j) pv[j] = (short)pk[j];
        *(bf16x8*)((char*)wq2 + ((size_t)(mw * 36 + t) * 64 + lane) * 16) = pv;
    }
}

// ---------------------------------------------------------------------------
// Conv implicit GEMM = round-4 structure with REGISTER-RESIDENT weights.
// Block = (b, 2 output rows); waves 2x2 (mw: cout half, nw: row).
// Wave preloads its 36 A-tiles (576 B/lane = 144 VGPRs) from wq2 before the
// barrier; the K-loop is then pure {ds_read_b128 -> 2 MFMA} with ZERO global
// loads on the critical path (r6/r9 lesson). launch_bounds(256,2): 256 VGPRs.
// Measured r10: best conv ~36 us, total 63.7 us.
// ---------------------------------------------------------------------------
__global__ __launch_bounds__(256, 2) void conv_mfma(
    const unsigned short* __restrict__ xt, const unsigned short* __restrict__ wq2,
    const float* __restrict__ bias, const float* __restrict__ scale,
    float* __restrict__ out) {
    __shared__ char xs[4 * XROWB];   // 58368 B -> 2 blocks/CU

    const int tid  = threadIdx.x;
    const int lane = tid & 63;
    const int wave = tid >> 6;
    const int lcol = lane & 15;
    const int kg   = lane >> 4;
    const int mw   = wave >> 1;      // cout half
    const int nw   = wave & 1;       // row within tile

    const int bid = blockIdx.x;
    const int s   = (bid & 7) * (NBLKC / 8) + (bid >> 3);   // XCD-bijective
    const int b   = s / HTILES;
    const int h0  = (s % HTILES) * 2;

    const char* xtc = (const char*)xt + (size_t)b * H_ * XROWB;

    // ---- preload all 36 weight tiles for this wave (coalesced, L2) ----
    bf16x8 wt[36];
    {
        const char* wp = (const char*)wq2 + (size_t)mw * 36 * 1024 + lane * 16;
#pragma unroll
        for (int t = 0; t < 36; ++t) wt[t] = *(const bf16x8*)(wp + t * 1024);
    }

    // ---- stage: wave r copies xt row h0-1+r linearly into LDS ----
    {
        const int r    = wave;
        const int xrow = h0 - 1 + r;
        char* dst = xs + r * XROWB;
        if (0 <= xrow && xrow < H_) {
            const char* src = xtc + (size_t)xrow * XROWB + lane * 16;
#pragma unroll
            for (int ch = 0; ch < 14; ++ch)
                GLOAD_LDS(src + ch * 1024, dst + ch * 1024, 16);
            GLOAD_LDS(xtc + (size_t)xrow * XROWB + 14336 + lane * 4,
                      dst + 14336, 4);
        } else {
            char* d = dst + lane * 16;
            const f32x4 z = {0.f, 0.f, 0.f, 0.f};
#pragma unroll
            for (int ch = 0; ch < 14; ++ch) *(f32x4*)(d + ch * 1024) = z;
            *(u32*)(dst + 14336 + lane * 4) = 0u;
        }
    }
    __syncthreads();

    // swizzle-adjusted K-offsets (verified r4)
    int koff[3][2];
#pragma unroll
    for (int dw = 0; dw < 3; ++dw) {
        const int key = ((lcol + dw) & 7) << 4;
        koff[dw][0] = (kg * 16) ^ key;
        koff[dw][1] = (64 + kg * 16) ^ key;
    }

    f32x4 acc[2][7];
#pragma unroll
    for (int m = 0; m < 2; ++m)
#pragma unroll
        for (int nf = 0; nf < 7; ++nf) acc[m][nf] = (f32x4){0.f, 0.f, 0.f, 0.f};

#pragma unroll
    for (int dh = 0; dh < 3; ++dh) {
        const char* rowb = xs + (nw + dh) * XROWB;
#pragma unroll
        for (int dw = 0; dw < 3; ++dw) {
            const char* colb = rowb + (lcol + dw) * CHUNK;
#pragma unroll
            for (int c0 = 0; c0 < 2; ++c0) {
                const int t0 = ((dh * 3 + dw) * 2 + c0) * 2;   // wt index
                const char* cb = colb + koff[dw][c0];
#pragma unroll
                for (int nf = 0; nf < 7; ++nf) {
                    const bf16x8 bv = *(const bf16x8*)(cb + nf * 2048);
                    acc[0][nf] = __builtin_amdgcn_mfma_f32_16x16x32_bf16(
                        wt[t0 + 0], bv, acc[0][nf], 0, 0, 0);
                    acc[1][nf] = __builtin_amdgcn_mfma_f32_16x16x32_bf16(
                        wt[t0 + 1], bv, acc[1][nf], 0, 0, 0);
                }
            }
        }
    }

    // ---- epilogue ----
    const float sc = scale[0];
    const int h = h0 + nw;
#pragma unroll
    for (int m = 0; m < 2; ++m) {
        const int cobase = mw * 32 + m * 16 + kg * 4;
        const f32x4 bs = *(const f32x4*)(bias + cobase);
#pragma unroll
        for (int nf = 0; nf < 7; ++nf) {
            const int col = nf * 16 + lcol;
#pragma unroll
            for (int rr = 0; rr < 4; ++rr)
                out[((size_t)(b * C_ + cobase + rr)) * HW + h * W_ + col] =
                    sc * (acc[m][nf][rr] + bs[rr]);
        }
    }
}

extern "C" void kernel_launch(void* const* d_in, const int* in_sizes, int n_in,
                              void* d_out, int out_size, void* d_ws,
                              size_t ws_size, hipStream_t stream) {
    const float* x     = (const float*)d_in[0];
    const float* w     = (const float*)d_in[1];
    const float* bias  = (const float*)d_in[2];
    const float* scale = (const float*)d_in[3];
    float* out         = (float*)d_out;

    unsigned short* wq2 = (unsigned short*)d_ws;  // 73728 B prepacked weights
    unsigned short* xt  = (unsigned short*)((char*)d_ws + WQ_OFF);

    xform<<<B_ * H_, 256, 0, stream>>>(x, xt, w, wq2);
    conv_mfma<<<NBLKC, 256, 0, stream>>>(xt, wq2, bias, scale, out);
}